// Round 1
// baseline (539.152 us; speedup 1.0000x reference)
//
#include <hip/hip_runtime.h>

// ---------------------------------------------------------------------------
// GraphNet: 2x GCNConv(128->128, relu) + global_mean_pool + Linear(128->16)
// N=50000 nodes, E=640000 edges, G=64 graphs. All fp32, indices int32.
// Strategy: aggregate-then-GEMM (GCN is linear: sum_j n_ji (x_j W) =
// (sum_j n_ji x_j) W). CSR-by-destination built per call (histogram + scan +
// fill), gather-only aggregation (one wave per node, float2 per lane).
// ---------------------------------------------------------------------------

__global__ void init_kernel(float* __restrict__ deg, int* __restrict__ cnt,
                            int* __restrict__ fill, float* __restrict__ pooled,
                            float* __restrict__ cntg, int n, int npool, int g) {
    int i = blockIdx.x * blockDim.x + threadIdx.x;
    if (i < n) {
        deg[i] = 1.0f;   // self-loop weight
        cnt[i] = 0;
        fill[i] = 0;
    }
    if (i < npool) pooled[i] = 0.0f;
    if (i < g) cntg[i] = 0.0f;
}

__global__ void deg_kernel(const int* __restrict__ col, const float* __restrict__ ew,
                           float* __restrict__ deg, int* __restrict__ cnt, int E) {
    int e = blockIdx.x * blockDim.x + threadIdx.x;
    if (e >= E) return;
    int c = col[e];
    atomicAdd(&deg[c], ew[e]);
    atomicAdd(&cnt[c], 1);
}

__global__ void dinv_kernel(const float* __restrict__ deg, float* __restrict__ dinv, int n) {
    int i = blockIdx.x * blockDim.x + threadIdx.x;
    if (i >= n) return;
    float d = deg[i];
    dinv[i] = (d > 0.0f) ? rsqrtf(d) : 0.0f;
}

// Single-block inclusive-scan -> exclusive rowptr. n ~ 50000, 1024 threads.
__global__ void scan_kernel(const int* __restrict__ cnt, int* __restrict__ rowptr, int n) {
    __shared__ int part[1024];
    int tid = threadIdx.x;
    int chunk = (n + 1023) / 1024;
    int start = tid * chunk;
    int end = min(start + chunk, n);
    int s = 0;
    for (int i = start; i < end; ++i) s += cnt[i];
    part[tid] = s;
    __syncthreads();
    for (int off = 1; off < 1024; off <<= 1) {
        int v = (tid >= off) ? part[tid - off] : 0;
        __syncthreads();
        part[tid] += v;
        __syncthreads();
    }
    int run = (tid == 0) ? 0 : part[tid - 1];
    for (int i = start; i < end; ++i) { rowptr[i] = run; run += cnt[i]; }
    if (start < n && end == n) rowptr[n] = run;  // total
}

__global__ void fill_kernel(const int* __restrict__ row, const int* __restrict__ col,
                            const float* __restrict__ ew, const float* __restrict__ dinv,
                            const int* __restrict__ rowptr, int* __restrict__ fill,
                            int* __restrict__ csr_src, float* __restrict__ csr_w, int E) {
    int e = blockIdx.x * blockDim.x + threadIdx.x;
    if (e >= E) return;
    int r = row[e], c = col[e];
    int pos = rowptr[c] + atomicAdd(&fill[c], 1);
    csr_src[pos] = r;
    csr_w[pos] = dinv[r] * ew[e] * dinv[c];
}

// One wave (64 lanes) per node; lane owns cols [2*lane, 2*lane+1].
// acc starts with the self-loop term dinv^2 * in[node], then gathers.
__global__ void agg_kernel(const float* __restrict__ in, const int* __restrict__ rowptr,
                           const int* __restrict__ src, const float* __restrict__ w,
                           const float* __restrict__ dinv, float* __restrict__ out, int n) {
    int node = blockIdx.x * (blockDim.x >> 6) + (threadIdx.x >> 6);
    if (node >= n) return;
    int lane = threadIdx.x & 63;
    const float2* __restrict__ in2 = (const float2*)in;
    float sl = dinv[node];
    sl *= sl;
    float2 v = in2[(size_t)node * 64 + lane];
    float ax = sl * v.x, ay = sl * v.y;
    int beg = rowptr[node], end = rowptr[node + 1];
    for (int idx = beg; idx < end; ++idx) {
        int j = src[idx];
        float ww = w[idx];
        float2 u = in2[(size_t)j * 64 + lane];
        ax += ww * u.x;
        ay += ww * u.y;
    }
    float2 r; r.x = ax; r.y = ay;
    ((float2*)out)[(size_t)node * 64 + lane] = r;
}

// out[i][c] = relu(sum_k A[i][k] * W[k][c] + b[c]); A: n x 128, W: 128 x 128.
// Block = 256 threads, 64 rows/block; thread computes 2 rows x 16 cols.
// W staged in 64 KB LDS (2 blocks/CU -> 8 waves/CU).
__global__ __launch_bounds__(256) void gemm_bias_relu(const float* __restrict__ A,
                                                      const float* __restrict__ W,
                                                      const float* __restrict__ bias,
                                                      float* __restrict__ out, int n) {
    __shared__ float Ws[128 * 128];
    {
        const float4* W4 = (const float4*)W;
        float4* Ws4 = (float4*)Ws;
        for (int t = threadIdx.x; t < 4096; t += 256) Ws4[t] = W4[t];
    }
    __syncthreads();

    int cg = (threadIdx.x & 7) * 16;     // column group base
    int rp = threadIdx.x >> 3;           // 0..31 row-pair id
    int row0 = blockIdx.x * 64 + rp * 2;
    int r0 = min(row0, n - 1);
    int r1 = min(row0 + 1, n - 1);
    const float4* __restrict__ A0 = (const float4*)(A + (size_t)r0 * 128);
    const float4* __restrict__ A1 = (const float4*)(A + (size_t)r1 * 128);

    float acc0[16], acc1[16];
#pragma unroll
    for (int c = 0; c < 16; ++c) { acc0[c] = 0.0f; acc1[c] = 0.0f; }

    for (int k4 = 0; k4 < 32; ++k4) {
        float4 a0 = A0[k4];
        float4 a1 = A1[k4];
#pragma unroll
        for (int kk = 0; kk < 4; ++kk) {
            int k = k4 * 4 + kk;
            const float* wrow = &Ws[k * 128 + cg];
            float av0 = (&a0.x)[kk];
            float av1 = (&a1.x)[kk];
#pragma unroll
            for (int c = 0; c < 16; ++c) {
                float wv = wrow[c];
                acc0[c] += av0 * wv;
                acc1[c] += av1 * wv;
            }
        }
    }

    if (row0 < n) {
#pragma unroll
        for (int c = 0; c < 16; ++c) {
            float v = acc0[c] + bias[cg + c];
            out[(size_t)row0 * 128 + cg + c] = fmaxf(v, 0.0f);
        }
    }
    if (row0 + 1 < n) {
#pragma unroll
        for (int c = 0; c < 16; ++c) {
            float v = acc1[c] + bias[cg + c];
            out[(size_t)(row0 + 1) * 128 + cg + c] = fmaxf(v, 0.0f);
        }
    }
}

// batch is sorted; block (g, s): binary-search graph bounds, reduce slice s.
// blockDim = 128 (one thread per column).
__global__ void pool_partial(const float* __restrict__ h, const int* __restrict__ batch,
                             float* __restrict__ pooled, float* __restrict__ cntg,
                             int n, int splits) {
    int g = blockIdx.x / splits;
    int s = blockIdx.x % splits;
    __shared__ int sb[2];
    if (threadIdx.x == 0) {
        int lo = 0, hi = n;
        while (lo < hi) { int m = (lo + hi) >> 1; if (batch[m] < g) lo = m + 1; else hi = m; }
        sb[0] = lo;
        lo = 0; hi = n;
        while (lo < hi) { int m = (lo + hi) >> 1; if (batch[m] < g + 1) lo = m + 1; else hi = m; }
        sb[1] = lo;
    }
    __syncthreads();
    int start = sb[0], end = sb[1];
    int len = end - start;
    if (s == 0 && threadIdx.x == 0) cntg[g] = (float)len;
    int a = start + (int)((long long)len * s / splits);
    int b = start + (int)((long long)len * (s + 1) / splits);
    int col = threadIdx.x;
    float acc = 0.0f;
    for (int i = a; i < b; ++i) acc += h[(size_t)i * 128 + col];
    atomicAdd(&pooled[g * 128 + col], acc);
}

__global__ void fc_kernel(const float* __restrict__ pooled, const float* __restrict__ cntg,
                          const float* __restrict__ Wfc, const float* __restrict__ bfc,
                          float* __restrict__ out, int G, int O) {
    int gid = blockIdx.x * blockDim.x + threadIdx.x;
    if (gid >= G * O) return;
    int g = gid / O, o = gid % O;
    float inv = 1.0f / fmaxf(cntg[g], 1.0f);
    float acc = bfc[o];
    for (int k = 0; k < 128; ++k) acc += pooled[g * 128 + k] * inv * Wfc[k * O + o];
    out[gid] = acc;
}

extern "C" void kernel_launch(void* const* d_in, const int* in_sizes, int n_in,
                              void* d_out, int out_size, void* d_ws, size_t ws_size,
                              hipStream_t stream) {
    const float* x     = (const float*)d_in[0];
    const int*   ei    = (const int*)d_in[1];
    const float* ew    = (const float*)d_in[2];
    const int*   batch = (const int*)d_in[3];
    const float* W1    = (const float*)d_in[4];
    const float* b1    = (const float*)d_in[5];
    const float* W2    = (const float*)d_in[6];
    const float* b2    = (const float*)d_in[7];
    const float* Wfc   = (const float*)d_in[8];
    const float* bfc   = (const float*)d_in[9];
    float* out = (float*)d_out;

    const int n = in_sizes[0] / 128;   // 50000
    const int E = in_sizes[2];         // 640000
    const int O = in_sizes[9];         // 16
    const int G = out_size / O;        // 64
    const int* row = ei;
    const int* col = ei + E;

    // Workspace carve (all 256B-aligned)
    char* p = (char*)d_ws;
    auto alloc = [&](size_t bytes) {
        char* r = p;
        p += (bytes + 255) & ~(size_t)255;
        return r;
    };
    float* deg     = (float*)alloc((size_t)n * 4);
    float* dinv    = (float*)alloc((size_t)n * 4);
    int*   cnt     = (int*)alloc((size_t)n * 4);
    int*   fill    = (int*)alloc((size_t)n * 4);
    int*   rowptr  = (int*)alloc((size_t)(n + 1) * 4);
    int*   csr_src = (int*)alloc((size_t)E * 4);
    float* csr_w   = (float*)alloc((size_t)E * 4);
    float* aggbuf  = (float*)alloc((size_t)n * 128 * 4);
    float* hbuf    = (float*)alloc((size_t)n * 128 * 4);
    float* pooled  = (float*)alloc((size_t)G * 128 * 4);
    float* cntg    = (float*)alloc((size_t)G * 4);

    // --- graph preprocessing (shared by both layers) ---
    init_kernel<<<(n + 255) / 256, 256, 0, stream>>>(deg, cnt, fill, pooled, cntg, n, G * 128, G);
    deg_kernel<<<(E + 255) / 256, 256, 0, stream>>>(col, ew, deg, cnt, E);
    dinv_kernel<<<(n + 255) / 256, 256, 0, stream>>>(deg, dinv, n);
    scan_kernel<<<1, 1024, 0, stream>>>(cnt, rowptr, n);
    fill_kernel<<<(E + 255) / 256, 256, 0, stream>>>(row, col, ew, dinv, rowptr, fill, csr_src, csr_w, E);

    // --- layer 1: h1 = relu(agg(x) @ W1 + b1) ---
    agg_kernel<<<(n + 3) / 4, 256, 0, stream>>>(x, rowptr, csr_src, csr_w, dinv, aggbuf, n);
    gemm_bias_relu<<<(n + 63) / 64, 256, 0, stream>>>(aggbuf, W1, b1, hbuf, n);

    // --- layer 2: h2 = relu(agg(h1) @ W2 + b2) (h2 overwrites h1) ---
    agg_kernel<<<(n + 3) / 4, 256, 0, stream>>>(hbuf, rowptr, csr_src, csr_w, dinv, aggbuf, n);
    gemm_bias_relu<<<(n + 63) / 64, 256, 0, stream>>>(aggbuf, W2, b2, hbuf, n);

    // --- pool + fc ---
    pool_partial<<<G * 8, 128, 0, stream>>>(hbuf, batch, pooled, cntg, n, 8);
    fc_kernel<<<(G * O + 255) / 256, 256, 0, stream>>>(pooled, cntg, Wfc, bfc, out, G, O);
}

// Round 3
// 435.302 us; speedup vs baseline: 1.2386x; 1.2386x over previous
//
#include <hip/hip_runtime.h>

// ---------------------------------------------------------------------------
// GraphNet: 2x GCNConv(128->128, relu) + global_mean_pool + Linear(128->16)
// N=50000 nodes, E=640000 edges, G=64 graphs. All fp32, indices int32.
// Strategy: aggregate-then-GEMM. CSR-by-destination built per call
// (histogram + 3-phase multiblock scan + fill), gather-only aggregation
// (one wave per node, float2 per lane, edge loop unrolled 4x for MLP).
// ---------------------------------------------------------------------------

typedef __attribute__((ext_vector_type(2))) float nfloat2;  // native vec for nt-store

__global__ void init_kernel(float* __restrict__ deg, int* __restrict__ cnt,
                            int* __restrict__ fill, float* __restrict__ pooled,
                            float* __restrict__ cntg, int n, int npool, int g) {
    int i = blockIdx.x * blockDim.x + threadIdx.x;
    if (i < n) {
        deg[i] = 1.0f;   // self-loop weight
        cnt[i] = 0;
        fill[i] = 0;
    }
    if (i < npool) pooled[i] = 0.0f;
    if (i < g) cntg[i] = 0.0f;
}

__global__ void deg_kernel(const int* __restrict__ col, const float* __restrict__ ew,
                           float* __restrict__ deg, int* __restrict__ cnt, int E) {
    int e = blockIdx.x * blockDim.x + threadIdx.x;
    if (e >= E) return;
    int c = col[e];
    atomicAdd(&deg[c], ew[e]);
    atomicAdd(&cnt[c], 1);
}

__global__ void dinv_kernel(const float* __restrict__ deg, float* __restrict__ dinv, int n) {
    int i = blockIdx.x * blockDim.x + threadIdx.x;
    if (i >= n) return;
    float d = deg[i];
    dinv[i] = (d > 0.0f) ? rsqrtf(d) : 0.0f;
}

// --- 3-phase multiblock exclusive scan of cnt[0..n) -> rowptr[0..n] ---
__global__ void block_sum_kernel(const int* __restrict__ cnt, int* __restrict__ bsum, int n) {
    __shared__ int s[256];
    int i = blockIdx.x * 256 + threadIdx.x;
    s[threadIdx.x] = (i < n) ? cnt[i] : 0;
    __syncthreads();
    for (int off = 128; off > 0; off >>= 1) {
        if (threadIdx.x < off) s[threadIdx.x] += s[threadIdx.x + off];
        __syncthreads();
    }
    if (threadIdx.x == 0) bsum[blockIdx.x] = s[0];
}

// single block, nb <= 256: exclusive offsets of block sums + total -> rowptr[n]
__global__ void scan_bsum_kernel(const int* __restrict__ bsum, int* __restrict__ boff,
                                 int* __restrict__ rowptr, int n, int nb) {
    __shared__ int s[256];
    int t = threadIdx.x;
    int v = (t < nb) ? bsum[t] : 0;
    s[t] = v;
    __syncthreads();
    for (int off = 1; off < 256; off <<= 1) {
        int u = (t >= off) ? s[t - off] : 0;
        __syncthreads();
        s[t] += u;
        __syncthreads();
    }
    if (t < nb) boff[t] = s[t] - v;           // exclusive block offset
    if (t == nb - 1) rowptr[n] = s[t];        // grand total
}

__global__ void rowptr_kernel(const int* __restrict__ cnt, const int* __restrict__ boff,
                              int* __restrict__ rowptr, int n) {
    __shared__ int s[256];
    int i = blockIdx.x * 256 + threadIdx.x;
    int t = threadIdx.x;
    int v = (i < n) ? cnt[i] : 0;
    s[t] = v;
    __syncthreads();
    for (int off = 1; off < 256; off <<= 1) {
        int u = (t >= off) ? s[t - off] : 0;
        __syncthreads();
        s[t] += u;
        __syncthreads();
    }
    if (i < n) rowptr[i] = boff[blockIdx.x] + s[t] - v;
}

__global__ void fill_kernel(const int* __restrict__ row, const int* __restrict__ col,
                            const float* __restrict__ ew, const float* __restrict__ dinv,
                            const int* __restrict__ rowptr, int* __restrict__ fill,
                            int* __restrict__ csr_src, float* __restrict__ csr_w, int E) {
    int e = blockIdx.x * blockDim.x + threadIdx.x;
    if (e >= E) return;
    int r = row[e], c = col[e];
    int pos = rowptr[c] + atomicAdd(&fill[c], 1);
    csr_src[pos] = r;
    csr_w[pos] = dinv[r] * ew[e] * dinv[c];
}

// One wave (64 lanes) per node; lane owns cols [2*lane, 2*lane+1].
// Edge loop unrolled 4x: 4 independent row gathers in flight per wave.
__global__ void agg_kernel(const float* __restrict__ in, const int* __restrict__ rowptr,
                           const int* __restrict__ src, const float* __restrict__ w,
                           const float* __restrict__ dinv, float* __restrict__ out, int n) {
    int node = blockIdx.x * (blockDim.x >> 6) + (threadIdx.x >> 6);
    if (node >= n) return;
    int lane = threadIdx.x & 63;
    const float2* __restrict__ in2 = (const float2*)in;
    float sl = dinv[node];
    sl *= sl;
    float2 v = in2[(size_t)node * 64 + lane];
    float ax = sl * v.x, ay = sl * v.y;
    int beg = rowptr[node], end = rowptr[node + 1];
    int idx = beg;
    for (; idx + 4 <= end; idx += 4) {
        int j0 = src[idx + 0], j1 = src[idx + 1], j2 = src[idx + 2], j3 = src[idx + 3];
        float w0 = w[idx + 0], w1 = w[idx + 1], w2 = w[idx + 2], w3 = w[idx + 3];
        float2 u0 = in2[(size_t)j0 * 64 + lane];
        float2 u1 = in2[(size_t)j1 * 64 + lane];
        float2 u2 = in2[(size_t)j2 * 64 + lane];
        float2 u3 = in2[(size_t)j3 * 64 + lane];
        ax += w0 * u0.x; ay += w0 * u0.y;
        ax += w1 * u1.x; ay += w1 * u1.y;
        ax += w2 * u2.x; ay += w2 * u2.y;
        ax += w3 * u3.x; ay += w3 * u3.y;
    }
    for (; idx < end; ++idx) {
        int j = src[idx];
        float ww = w[idx];
        float2 u = in2[(size_t)j * 64 + lane];
        ax += ww * u.x;
        ay += ww * u.y;
    }
    nfloat2 r; r.x = ax; r.y = ay;
    __builtin_nontemporal_store(r, &((nfloat2*)out)[(size_t)node * 64 + lane]);
}

// out[i][c] = relu(sum_k A[i][k] * W[k][c] + b[c]); A: n x 128, W: 128 x 128.
// Block = 256 threads, 64 rows/block; thread computes 2 rows x 16 cols.
__global__ __launch_bounds__(256) void gemm_bias_relu(const float* __restrict__ A,
                                                      const float* __restrict__ W,
                                                      const float* __restrict__ bias,
                                                      float* __restrict__ out, int n) {
    __shared__ float Ws[128 * 128];
    {
        const float4* W4 = (const float4*)W;
        float4* Ws4 = (float4*)Ws;
        for (int t = threadIdx.x; t < 4096; t += 256) Ws4[t] = W4[t];
    }
    __syncthreads();

    int cg = (threadIdx.x & 7) * 16;     // column group base
    int rp = threadIdx.x >> 3;           // 0..31 row-pair id
    int row0 = blockIdx.x * 64 + rp * 2;
    int r0 = min(row0, n - 1);
    int r1 = min(row0 + 1, n - 1);
    const float4* __restrict__ A0 = (const float4*)(A + (size_t)r0 * 128);
    const float4* __restrict__ A1 = (const float4*)(A + (size_t)r1 * 128);

    float acc0[16], acc1[16];
#pragma unroll
    for (int c = 0; c < 16; ++c) { acc0[c] = 0.0f; acc1[c] = 0.0f; }

    for (int k4 = 0; k4 < 32; ++k4) {
        float4 a0 = A0[k4];
        float4 a1 = A1[k4];
#pragma unroll
        for (int kk = 0; kk < 4; ++kk) {
            int k = k4 * 4 + kk;
            const float* wrow = &Ws[k * 128 + cg];
            float av0 = (&a0.x)[kk];
            float av1 = (&a1.x)[kk];
#pragma unroll
            for (int c = 0; c < 16; ++c) {
                float wv = wrow[c];
                acc0[c] += av0 * wv;
                acc1[c] += av1 * wv;
            }
        }
    }

    if (row0 < n) {
#pragma unroll
        for (int c = 0; c < 16; ++c) {
            float v = acc0[c] + bias[cg + c];
            out[(size_t)row0 * 128 + cg + c] = fmaxf(v, 0.0f);
        }
    }
    if (row0 + 1 < n) {
#pragma unroll
        for (int c = 0; c < 16; ++c) {
            float v = acc1[c] + bias[cg + c];
            out[(size_t)(row0 + 1) * 128 + cg + c] = fmaxf(v, 0.0f);
        }
    }
}

// batch is sorted; block (g, s): binary-search graph bounds, reduce slice s.
__global__ void pool_partial(const float* __restrict__ h, const int* __restrict__ batch,
                             float* __restrict__ pooled, float* __restrict__ cntg,
                             int n, int splits) {
    int g = blockIdx.x / splits;
    int s = blockIdx.x % splits;
    __shared__ int sb[2];
    if (threadIdx.x == 0) {
        int lo = 0, hi = n;
        while (lo < hi) { int m = (lo + hi) >> 1; if (batch[m] < g) lo = m + 1; else hi = m; }
        sb[0] = lo;
        lo = 0; hi = n;
        while (lo < hi) { int m = (lo + hi) >> 1; if (batch[m] < g + 1) lo = m + 1; else hi = m; }
        sb[1] = lo;
    }
    __syncthreads();
    int start = sb[0], end = sb[1];
    int len = end - start;
    if (s == 0 && threadIdx.x == 0) cntg[g] = (float)len;
    int a = start + (int)((long long)len * s / splits);
    int b = start + (int)((long long)len * (s + 1) / splits);
    int col = threadIdx.x;
    float acc = 0.0f;
    for (int i = a; i < b; ++i) acc += h[(size_t)i * 128 + col];
    atomicAdd(&pooled[g * 128 + col], acc);
}

__global__ void fc_kernel(const float* __restrict__ pooled, const float* __restrict__ cntg,
                          const float* __restrict__ Wfc, const float* __restrict__ bfc,
                          float* __restrict__ out, int G, int O) {
    int gid = blockIdx.x * blockDim.x + threadIdx.x;
    if (gid >= G * O) return;
    int g = gid / O, o = gid % O;
    float inv = 1.0f / fmaxf(cntg[g], 1.0f);
    float acc = bfc[o];
    for (int k = 0; k < 128; ++k) acc += pooled[g * 128 + k] * inv * Wfc[k * O + o];
    out[gid] = acc;
}

extern "C" void kernel_launch(void* const* d_in, const int* in_sizes, int n_in,
                              void* d_out, int out_size, void* d_ws, size_t ws_size,
                              hipStream_t stream) {
    const float* x     = (const float*)d_in[0];
    const int*   ei    = (const int*)d_in[1];
    const float* ew    = (const float*)d_in[2];
    const int*   batch = (const int*)d_in[3];
    const float* W1    = (const float*)d_in[4];
    const float* b1    = (const float*)d_in[5];
    const float* W2    = (const float*)d_in[6];
    const float* b2    = (const float*)d_in[7];
    const float* Wfc   = (const float*)d_in[8];
    const float* bfc   = (const float*)d_in[9];
    float* out = (float*)d_out;

    const int n = in_sizes[0] / 128;   // 50000
    const int E = in_sizes[2];         // 640000
    const int O = in_sizes[9];         // 16
    const int G = out_size / O;        // 64
    const int* row = ei;
    const int* col = ei + E;
    const int NB = (n + 255) / 256;    // scan blocks (196)

    // Workspace carve (all 256B-aligned)
    char* p = (char*)d_ws;
    auto alloc = [&](size_t bytes) {
        char* r = p;
        p += (bytes + 255) & ~(size_t)255;
        return r;
    };
    float* deg     = (float*)alloc((size_t)n * 4);
    float* dinv    = (float*)alloc((size_t)n * 4);
    int*   cnt     = (int*)alloc((size_t)n * 4);
    int*   fill    = (int*)alloc((size_t)n * 4);
    int*   rowptr  = (int*)alloc((size_t)(n + 1) * 4);
    int*   bsum    = (int*)alloc((size_t)NB * 4);
    int*   boff    = (int*)alloc((size_t)NB * 4);
    int*   csr_src = (int*)alloc((size_t)E * 4);
    float* csr_w   = (float*)alloc((size_t)E * 4);
    float* aggbuf  = (float*)alloc((size_t)n * 128 * 4);
    float* hbuf    = (float*)alloc((size_t)n * 128 * 4);
    float* pooled  = (float*)alloc((size_t)G * 128 * 4);
    float* cntg    = (float*)alloc((size_t)G * 4);

    // --- graph preprocessing (shared by both layers) ---
    init_kernel<<<(n + 255) / 256, 256, 0, stream>>>(deg, cnt, fill, pooled, cntg, n, G * 128, G);
    deg_kernel<<<(E + 255) / 256, 256, 0, stream>>>(col, ew, deg, cnt, E);
    dinv_kernel<<<(n + 255) / 256, 256, 0, stream>>>(deg, dinv, n);
    block_sum_kernel<<<NB, 256, 0, stream>>>(cnt, bsum, n);
    scan_bsum_kernel<<<1, 256, 0, stream>>>(bsum, boff, rowptr, n, NB);
    rowptr_kernel<<<NB, 256, 0, stream>>>(cnt, boff, rowptr, n);
    fill_kernel<<<(E + 255) / 256, 256, 0, stream>>>(row, col, ew, dinv, rowptr, fill, csr_src, csr_w, E);

    // --- layer 1: h1 = relu(agg(x) @ W1 + b1) ---
    agg_kernel<<<(n + 3) / 4, 256, 0, stream>>>(x, rowptr, csr_src, csr_w, dinv, aggbuf, n);
    gemm_bias_relu<<<(n + 63) / 64, 256, 0, stream>>>(aggbuf, W1, b1, hbuf, n);

    // --- layer 2: h2 = relu(agg(h1) @ W2 + b2) (h2 overwrites h1) ---
    agg_kernel<<<(n + 3) / 4, 256, 0, stream>>>(hbuf, rowptr, csr_src, csr_w, dinv, aggbuf, n);
    gemm_bias_relu<<<(n + 63) / 64, 256, 0, stream>>>(aggbuf, W2, b2, hbuf, n);

    // --- pool + fc ---
    pool_partial<<<G * 8, 128, 0, stream>>>(hbuf, batch, pooled, cntg, n, 8);
    fc_kernel<<<(G * O + 255) / 256, 256, 0, stream>>>(pooled, cntg, Wfc, bfc, out, G, O);
}

// Round 4
// 352.554 us; speedup vs baseline: 1.5293x; 1.2347x over previous
//
#include <hip/hip_runtime.h>

// ---------------------------------------------------------------------------
// GraphNet: 2x GCNConv(128->128, relu) + global_mean_pool + Linear(128->16)
// N=50000 nodes, E=640000 edges, G=64 graphs. All fp32, indices int32.
// Strategy: aggregate-then-GEMM. CSR-by-dest built with ONE atomic pass
// (rank = atomicAdd histogram), multiblock scan, atomic-free scatter of
// packed int2 (src, ew). deg from CSR segmented sum; dinv[src] folded into
// a streaming scale pass, dinv[dst] into agg epilogue. GEMM: W in LDS with
// strided-granule column tile (conflict-free b128 reads), 4 rows x 16 cols
// per thread.
// ---------------------------------------------------------------------------

typedef __attribute__((ext_vector_type(2))) float nfloat2;  // native vec for nt-store

__global__ void init_kernel(int* __restrict__ cnt, float* __restrict__ pooled,
                            float* __restrict__ cntg, int n, int npool, int g) {
    int i = blockIdx.x * blockDim.x + threadIdx.x;
    if (i < n) cnt[i] = 0;
    if (i < npool) pooled[i] = 0.0f;
    if (i < g) cntg[i] = 0.0f;
}

// ONE atomic per edge: rank within destination bucket + histogram.
__global__ void rank_kernel(const int* __restrict__ col, int* __restrict__ cnt,
                            int* __restrict__ rank, int E) {
    int e = blockIdx.x * blockDim.x + threadIdx.x;
    if (e >= E) return;
    rank[e] = atomicAdd(&cnt[col[e]], 1);
}

// --- 3-phase multiblock exclusive scan of cnt[0..n) -> rowptr[0..n] ---
__global__ void block_sum_kernel(const int* __restrict__ cnt, int* __restrict__ bsum, int n) {
    __shared__ int s[256];
    int i = blockIdx.x * 256 + threadIdx.x;
    s[threadIdx.x] = (i < n) ? cnt[i] : 0;
    __syncthreads();
    for (int off = 128; off > 0; off >>= 1) {
        if (threadIdx.x < off) s[threadIdx.x] += s[threadIdx.x + off];
        __syncthreads();
    }
    if (threadIdx.x == 0) bsum[blockIdx.x] = s[0];
}

__global__ void scan_bsum_kernel(const int* __restrict__ bsum, int* __restrict__ boff,
                                 int* __restrict__ rowptr, int n, int nb) {
    __shared__ int s[256];
    int t = threadIdx.x;
    int v = (t < nb) ? bsum[t] : 0;
    s[t] = v;
    __syncthreads();
    for (int off = 1; off < 256; off <<= 1) {
        int u = (t >= off) ? s[t - off] : 0;
        __syncthreads();
        s[t] += u;
        __syncthreads();
    }
    if (t < nb) boff[t] = s[t] - v;           // exclusive block offset
    if (t == nb - 1) rowptr[n] = s[t];        // grand total
}

__global__ void rowptr_kernel(const int* __restrict__ cnt, const int* __restrict__ boff,
                              int* __restrict__ rowptr, int n) {
    __shared__ int s[256];
    int i = blockIdx.x * 256 + threadIdx.x;
    int t = threadIdx.x;
    int v = (i < n) ? cnt[i] : 0;
    s[t] = v;
    __syncthreads();
    for (int off = 1; off < 256; off <<= 1) {
        int u = (t >= off) ? s[t - off] : 0;
        __syncthreads();
        s[t] += u;
        __syncthreads();
    }
    if (i < n) rowptr[i] = boff[blockIdx.x] + s[t] - v;
}

// Atomic-free scatter: pos = rowptr[col] + rank. Packed (src, ew-bits).
__global__ void scatter_kernel(const int* __restrict__ row, const int* __restrict__ col,
                               const float* __restrict__ ew, const int* __restrict__ rank,
                               const int* __restrict__ rowptr, int2* __restrict__ csr, int E) {
    int e = blockIdx.x * blockDim.x + threadIdx.x;
    if (e >= E) return;
    int pos = rowptr[col[e]] + rank[e];
    int2 v;
    v.x = row[e];
    v.y = __float_as_int(ew[e]);
    csr[pos] = v;
}

// deg[i] = 1 + sum of incoming ew; dinv = rsqrt(deg). No atomics.
__global__ void deginv_kernel(const int2* __restrict__ csr, const int* __restrict__ rowptr,
                              float* __restrict__ dinv, int n) {
    int i = blockIdx.x * blockDim.x + threadIdx.x;
    if (i >= n) return;
    int beg = rowptr[i], end = rowptr[i + 1];
    float d = 1.0f;   // self-loop
    for (int k = beg; k < end; ++k) d += __int_as_float(csr[k].y);
    dinv[i] = rsqrtf(d);
}

// csr.y <- dinv[src] * ew   (dinv[dst] applied in agg epilogue)
__global__ void scale_kernel(int2* __restrict__ csr, const float* __restrict__ dinv, int T) {
    int i = blockIdx.x * blockDim.x + threadIdx.x;
    if (i >= T) return;
    int2 v = csr[i];
    v.y = __float_as_int(dinv[v.x] * __int_as_float(v.y));
    csr[i] = v;
}

// One wave per node; lane owns cols [2*lane, 2*lane+1]. Edge loop 4x unrolled.
// out = dinv[dst] * ( sum_e w_e * x[src_e]  +  dinv[dst] * x[dst] )
__global__ void agg_kernel(const float* __restrict__ in, const int* __restrict__ rowptr,
                           const int2* __restrict__ csr, const float* __restrict__ dinv,
                           float* __restrict__ out, int n) {
    int node = blockIdx.x * (blockDim.x >> 6) + (threadIdx.x >> 6);
    if (node >= n) return;
    int lane = threadIdx.x & 63;
    const float2* __restrict__ in2 = (const float2*)in;
    float di = dinv[node];
    float2 v = in2[(size_t)node * 64 + lane];
    float ax = di * v.x, ay = di * v.y;
    int beg = rowptr[node], end = rowptr[node + 1];
    int idx = beg;
    for (; idx + 4 <= end; idx += 4) {
        int2 e0 = csr[idx + 0], e1 = csr[idx + 1], e2 = csr[idx + 2], e3 = csr[idx + 3];
        float2 u0 = in2[(size_t)e0.x * 64 + lane];
        float2 u1 = in2[(size_t)e1.x * 64 + lane];
        float2 u2 = in2[(size_t)e2.x * 64 + lane];
        float2 u3 = in2[(size_t)e3.x * 64 + lane];
        float w0 = __int_as_float(e0.y), w1 = __int_as_float(e1.y);
        float w2 = __int_as_float(e2.y), w3 = __int_as_float(e3.y);
        ax += w0 * u0.x; ay += w0 * u0.y;
        ax += w1 * u1.x; ay += w1 * u1.y;
        ax += w2 * u2.x; ay += w2 * u2.y;
        ax += w3 * u3.x; ay += w3 * u3.y;
    }
    for (; idx < end; ++idx) {
        int2 e0 = csr[idx];
        float ww = __int_as_float(e0.y);
        float2 u = in2[(size_t)e0.x * 64 + lane];
        ax += ww * u.x;
        ay += ww * u.y;
    }
    nfloat2 r; r.x = ax * di; r.y = ay * di;
    __builtin_nontemporal_store(r, &((nfloat2*)out)[(size_t)node * 64 + lane]);
}

// out[i][c] = relu(sum_k A[i][k]*W[k][c] + b[c]); A: n x 128, W: 128 x 128.
// Block 256 threads = 128 rows. Thread: 4 rows x 16 cols, cols as 4 float4
// granules gc = (t&7) + 8m -> wave's 8 col-groups hit bank-quads 0,4,..,28:
// conflict-free ds_read_b128 with 8-lane broadcast.
__global__ __launch_bounds__(256) void gemm_bias_relu(const float* __restrict__ A,
                                                      const float* __restrict__ W,
                                                      const float* __restrict__ bias,
                                                      float* __restrict__ out, int n) {
    __shared__ float4 Ws[128 * 32];   // [k][granule]
    {
        const float4* W4 = (const float4*)W;
        for (int t = threadIdx.x; t < 4096; t += 256) Ws[t] = W4[t];
    }
    __syncthreads();

    int colg = threadIdx.x & 7;          // 0..7
    int rowg = threadIdx.x >> 3;         // 0..31
    int row0 = blockIdx.x * 128 + rowg * 4;

    const float4* Ap[4];
#pragma unroll
    for (int r = 0; r < 4; ++r) {
        int rr = min(row0 + r, n - 1);
        Ap[r] = (const float4*)(A + (size_t)rr * 128);
    }

    float acc[4][4][4];   // [row][granule m][elem j]
#pragma unroll
    for (int r = 0; r < 4; ++r)
#pragma unroll
        for (int m = 0; m < 4; ++m)
#pragma unroll
            for (int j = 0; j < 4; ++j) acc[r][m][j] = 0.0f;

    for (int k4 = 0; k4 < 32; ++k4) {
        float4 a[4];
#pragma unroll
        for (int r = 0; r < 4; ++r) a[r] = Ap[r][k4];
#pragma unroll
        for (int kk = 0; kk < 4; ++kk) {
            float4 w[4];
#pragma unroll
            for (int m = 0; m < 4; ++m) w[m] = Ws[(k4 * 4 + kk) * 32 + colg + 8 * m];
#pragma unroll
            for (int r = 0; r < 4; ++r) {
                float av = (&a[r].x)[kk];
#pragma unroll
                for (int m = 0; m < 4; ++m) {
#pragma unroll
                    for (int j = 0; j < 4; ++j) acc[r][m][j] += av * (&w[m].x)[j];
                }
            }
        }
    }

    float4 bz[4];
#pragma unroll
    for (int m = 0; m < 4; ++m) bz[m] = ((const float4*)bias)[colg + 8 * m];

#pragma unroll
    for (int r = 0; r < 4; ++r) {
        if (row0 + r < n) {
            float4* orow = (float4*)(out + (size_t)(row0 + r) * 128);
#pragma unroll
            for (int m = 0; m < 4; ++m) {
                float4 o;
                o.x = fmaxf(acc[r][m][0] + bz[m].x, 0.0f);
                o.y = fmaxf(acc[r][m][1] + bz[m].y, 0.0f);
                o.z = fmaxf(acc[r][m][2] + bz[m].z, 0.0f);
                o.w = fmaxf(acc[r][m][3] + bz[m].w, 0.0f);
                orow[colg + 8 * m] = o;
            }
        }
    }
}

// batch is sorted; block (g, s): binary-search graph bounds, reduce slice s.
__global__ void pool_partial(const float* __restrict__ h, const int* __restrict__ batch,
                             float* __restrict__ pooled, float* __restrict__ cntg,
                             int n, int splits) {
    int g = blockIdx.x / splits;
    int s = blockIdx.x % splits;
    __shared__ int sb[2];
    if (threadIdx.x == 0) {
        int lo = 0, hi = n;
        while (lo < hi) { int m = (lo + hi) >> 1; if (batch[m] < g) lo = m + 1; else hi = m; }
        sb[0] = lo;
        lo = 0; hi = n;
        while (lo < hi) { int m = (lo + hi) >> 1; if (batch[m] < g + 1) lo = m + 1; else hi = m; }
        sb[1] = lo;
    }
    __syncthreads();
    int start = sb[0], end = sb[1];
    int len = end - start;
    if (s == 0 && threadIdx.x == 0) cntg[g] = (float)len;
    int a = start + (int)((long long)len * s / splits);
    int b = start + (int)((long long)len * (s + 1) / splits);
    int col = threadIdx.x;
    float acc = 0.0f;
    for (int i = a; i < b; ++i) acc += h[(size_t)i * 128 + col];
    atomicAdd(&pooled[g * 128 + col], acc);
}

__global__ void fc_kernel(const float* __restrict__ pooled, const float* __restrict__ cntg,
                          const float* __restrict__ Wfc, const float* __restrict__ bfc,
                          float* __restrict__ out, int G, int O) {
    int gid = blockIdx.x * blockDim.x + threadIdx.x;
    if (gid >= G * O) return;
    int g = gid / O, o = gid % O;
    float inv = 1.0f / fmaxf(cntg[g], 1.0f);
    float acc = bfc[o];
    for (int k = 0; k < 128; ++k) acc += pooled[g * 128 + k] * inv * Wfc[k * O + o];
    out[gid] = acc;
}

extern "C" void kernel_launch(void* const* d_in, const int* in_sizes, int n_in,
                              void* d_out, int out_size, void* d_ws, size_t ws_size,
                              hipStream_t stream) {
    const float* x     = (const float*)d_in[0];
    const int*   ei    = (const int*)d_in[1];
    const float* ew    = (const float*)d_in[2];
    const int*   batch = (const int*)d_in[3];
    const float* W1    = (const float*)d_in[4];
    const float* b1    = (const float*)d_in[5];
    const float* W2    = (const float*)d_in[6];
    const float* b2    = (const float*)d_in[7];
    const float* Wfc   = (const float*)d_in[8];
    const float* bfc   = (const float*)d_in[9];
    float* out = (float*)d_out;

    const int n = in_sizes[0] / 128;   // 50000
    const int E = in_sizes[2];         // 640000
    const int O = in_sizes[9];         // 16
    const int G = out_size / O;        // 64
    const int* row = ei;
    const int* col = ei + E;
    const int NB = (n + 255) / 256;    // scan blocks (196)

    // Workspace carve (all 256B-aligned)
    char* p = (char*)d_ws;
    auto alloc = [&](size_t bytes) {
        char* r = p;
        p += (bytes + 255) & ~(size_t)255;
        return r;
    };
    float* dinv    = (float*)alloc((size_t)n * 4);
    int*   cnt     = (int*)alloc((size_t)n * 4);
    int*   rank    = (int*)alloc((size_t)E * 4);
    int*   rowptr  = (int*)alloc((size_t)(n + 1) * 4);
    int*   bsum    = (int*)alloc((size_t)NB * 4);
    int*   boff    = (int*)alloc((size_t)NB * 4);
    int2*  csr     = (int2*)alloc((size_t)E * 8);
    float* aggbuf  = (float*)alloc((size_t)n * 128 * 4);
    float* hbuf    = (float*)alloc((size_t)n * 128 * 4);
    float* pooled  = (float*)alloc((size_t)G * 128 * 4);
    float* cntg    = (float*)alloc((size_t)G * 4);

    // --- CSR build: one atomic pass + scan + atomic-free scatter ---
    init_kernel<<<(n + 255) / 256, 256, 0, stream>>>(cnt, pooled, cntg, n, G * 128, G);
    rank_kernel<<<(E + 255) / 256, 256, 0, stream>>>(col, cnt, rank, E);
    block_sum_kernel<<<NB, 256, 0, stream>>>(cnt, bsum, n);
    scan_bsum_kernel<<<1, 256, 0, stream>>>(bsum, boff, rowptr, n, NB);
    rowptr_kernel<<<NB, 256, 0, stream>>>(cnt, boff, rowptr, n);
    scatter_kernel<<<(E + 255) / 256, 256, 0, stream>>>(row, col, ew, rank, rowptr, csr, E);
    deginv_kernel<<<(n + 255) / 256, 256, 0, stream>>>(csr, rowptr, dinv, n);
    scale_kernel<<<(E + 255) / 256, 256, 0, stream>>>(csr, dinv, E);

    // --- layer 1: h1 = relu(agg(x) @ W1 + b1) ---
    agg_kernel<<<(n + 3) / 4, 256, 0, stream>>>(x, rowptr, csr, dinv, aggbuf, n);
    gemm_bias_relu<<<(n + 127) / 128, 256, 0, stream>>>(aggbuf, W1, b1, hbuf, n);

    // --- layer 2: h2 = relu(agg(h1) @ W2 + b2) ---
    agg_kernel<<<(n + 3) / 4, 256, 0, stream>>>(hbuf, rowptr, csr, dinv, aggbuf, n);
    gemm_bias_relu<<<(n + 127) / 128, 256, 0, stream>>>(aggbuf, W2, b2, hbuf, n);

    // --- pool + fc ---
    pool_partial<<<G * 8, 128, 0, stream>>>(hbuf, batch, pooled, cntg, n, 8);
    fc_kernel<<<(G * O + 255) / 256, 256, 0, stream>>>(pooled, cntg, Wfc, bfc, out, G, O);
}

// Round 5
// 351.875 us; speedup vs baseline: 1.5322x; 1.0019x over previous
//
#include <hip/hip_runtime.h>

// ---------------------------------------------------------------------------
// GraphNet: 2x GCNConv(128->128, relu) + global_mean_pool + Linear(128->16)
// N=50000 nodes, E=640000 edges, G=64 graphs. All fp32, indices int32.
// Strategy: aggregate-then-GEMM. CSR-by-dest built with ONE atomic pass
// (rank = atomicAdd histogram), multiblock scan, atomic-free scatter of
// packed int2 (src, ew). Agg: one HALF-WAVE per node, float4/lane, 4x
// unrolled edge loop -> 8 outstanding 512B gathers per wave. GEMM: W in LDS
// with strided-granule column tile (conflict-free b128), 4 rows x 16 cols.
// ---------------------------------------------------------------------------

typedef __attribute__((ext_vector_type(4))) float nfloat4;  // native vec for nt-store

__global__ void init_kernel(int* __restrict__ cnt, float* __restrict__ pooled,
                            float* __restrict__ cntg, int n, int npool, int g) {
    int i = blockIdx.x * blockDim.x + threadIdx.x;
    if (i < n) cnt[i] = 0;
    if (i < npool) pooled[i] = 0.0f;
    if (i < g) cntg[i] = 0.0f;
}

// ONE atomic per edge: rank within destination bucket + histogram.
__global__ void rank_kernel(const int* __restrict__ col, int* __restrict__ cnt,
                            int* __restrict__ rank, int E) {
    int e = blockIdx.x * blockDim.x + threadIdx.x;
    if (e >= E) return;
    rank[e] = atomicAdd(&cnt[col[e]], 1);
}

// --- 3-phase multiblock exclusive scan of cnt[0..n) -> rowptr[0..n] ---
__global__ void block_sum_kernel(const int* __restrict__ cnt, int* __restrict__ bsum, int n) {
    __shared__ int s[256];
    int i = blockIdx.x * 256 + threadIdx.x;
    s[threadIdx.x] = (i < n) ? cnt[i] : 0;
    __syncthreads();
    for (int off = 128; off > 0; off >>= 1) {
        if (threadIdx.x < off) s[threadIdx.x] += s[threadIdx.x + off];
        __syncthreads();
    }
    if (threadIdx.x == 0) bsum[blockIdx.x] = s[0];
}

__global__ void scan_bsum_kernel(const int* __restrict__ bsum, int* __restrict__ boff,
                                 int* __restrict__ rowptr, int n, int nb) {
    __shared__ int s[256];
    int t = threadIdx.x;
    int v = (t < nb) ? bsum[t] : 0;
    s[t] = v;
    __syncthreads();
    for (int off = 1; off < 256; off <<= 1) {
        int u = (t >= off) ? s[t - off] : 0;
        __syncthreads();
        s[t] += u;
        __syncthreads();
    }
    if (t < nb) boff[t] = s[t] - v;           // exclusive block offset
    if (t == nb - 1) rowptr[n] = s[t];        // grand total
}

__global__ void rowptr_kernel(const int* __restrict__ cnt, const int* __restrict__ boff,
                              int* __restrict__ rowptr, int n) {
    __shared__ int s[256];
    int i = blockIdx.x * 256 + threadIdx.x;
    int t = threadIdx.x;
    int v = (i < n) ? cnt[i] : 0;
    s[t] = v;
    __syncthreads();
    for (int off = 1; off < 256; off <<= 1) {
        int u = (t >= off) ? s[t - off] : 0;
        __syncthreads();
        s[t] += u;
        __syncthreads();
    }
    if (i < n) rowptr[i] = boff[blockIdx.x] + s[t] - v;
}

// Atomic-free scatter: pos = rowptr[col] + rank. Packed (src, ew-bits).
__global__ void scatter_kernel(const int* __restrict__ row, const int* __restrict__ col,
                               const float* __restrict__ ew, const int* __restrict__ rank,
                               const int* __restrict__ rowptr, int2* __restrict__ csr, int E) {
    int e = blockIdx.x * blockDim.x + threadIdx.x;
    if (e >= E) return;
    int pos = rowptr[col[e]] + rank[e];
    int2 v;
    v.x = row[e];
    v.y = __float_as_int(ew[e]);
    csr[pos] = v;
}

// deg[i] = 1 + sum of incoming ew; dinv = rsqrt(deg). No atomics.
__global__ void deginv_kernel(const int2* __restrict__ csr, const int* __restrict__ rowptr,
                              float* __restrict__ dinv, int n) {
    int i = blockIdx.x * blockDim.x + threadIdx.x;
    if (i >= n) return;
    int beg = rowptr[i], end = rowptr[i + 1];
    float d = 1.0f;   // self-loop
    for (int k = beg; k < end; ++k) d += __int_as_float(csr[k].y);
    dinv[i] = rsqrtf(d);
}

// csr.y <- dinv[src] * ew   (dinv[dst] applied in agg epilogue)
__global__ void scale_kernel(int2* __restrict__ csr, const float* __restrict__ dinv, int T) {
    int i = blockIdx.x * blockDim.x + threadIdx.x;
    if (i >= T) return;
    int2 v = csr[i];
    v.y = __float_as_int(dinv[v.x] * __int_as_float(v.y));
    csr[i] = v;
}

// One HALF-WAVE (32 lanes) per node; lane owns float4 [4*lane..4*lane+3].
// Edge loop unrolled 4x -> 8 independent 512B gathers in flight per wave.
// out = dinv[dst] * ( sum_e w_e * x[src_e]  +  dinv[dst] * x[dst] )
__global__ __launch_bounds__(256) void agg_kernel(const float* __restrict__ in,
                                                  const int* __restrict__ rowptr,
                                                  const int2* __restrict__ csr,
                                                  const float* __restrict__ dinv,
                                                  float* __restrict__ out, int n) {
    int node = blockIdx.x * 8 + (threadIdx.x >> 5);
    if (node >= n) return;
    int lane = threadIdx.x & 31;
    const float4* __restrict__ in4 = (const float4*)in;   // 32 float4 per row
    float di = dinv[node];
    float4 v = in4[(size_t)node * 32 + lane];
    float ax = di * v.x, ay = di * v.y, az = di * v.z, aw = di * v.w;
    int beg = rowptr[node], end = rowptr[node + 1];
    int idx = beg;
    for (; idx + 4 <= end; idx += 4) {
        int2 e0 = csr[idx + 0], e1 = csr[idx + 1], e2 = csr[idx + 2], e3 = csr[idx + 3];
        float4 u0 = in4[(size_t)e0.x * 32 + lane];
        float4 u1 = in4[(size_t)e1.x * 32 + lane];
        float4 u2 = in4[(size_t)e2.x * 32 + lane];
        float4 u3 = in4[(size_t)e3.x * 32 + lane];
        float w0 = __int_as_float(e0.y), w1 = __int_as_float(e1.y);
        float w2 = __int_as_float(e2.y), w3 = __int_as_float(e3.y);
        ax += w0 * u0.x; ay += w0 * u0.y; az += w0 * u0.z; aw += w0 * u0.w;
        ax += w1 * u1.x; ay += w1 * u1.y; az += w1 * u1.z; aw += w1 * u1.w;
        ax += w2 * u2.x; ay += w2 * u2.y; az += w2 * u2.z; aw += w2 * u2.w;
        ax += w3 * u3.x; ay += w3 * u3.y; az += w3 * u3.z; aw += w3 * u3.w;
    }
    for (; idx < end; ++idx) {
        int2 e0 = csr[idx];
        float ww = __int_as_float(e0.y);
        float4 u = in4[(size_t)e0.x * 32 + lane];
        ax += ww * u.x; ay += ww * u.y; az += ww * u.z; aw += ww * u.w;
    }
    nfloat4 r;
    r.x = ax * di; r.y = ay * di; r.z = az * di; r.w = aw * di;
    __builtin_nontemporal_store(r, &((nfloat4*)out)[(size_t)node * 32 + lane]);
}

// out[i][c] = relu(sum_k A[i][k]*W[k][c] + b[c]); A: n x 128, W: 128 x 128.
// Block 256 threads = 128 rows. Thread: 4 rows x 16 cols, cols as 4 float4
// granules gc = (t&7) + 8m -> wave's 8 col-groups hit bank-quads 0,4,..,28:
// conflict-free ds_read_b128 with 8-lane broadcast.
__global__ __launch_bounds__(256) void gemm_bias_relu(const float* __restrict__ A,
                                                      const float* __restrict__ W,
                                                      const float* __restrict__ bias,
                                                      float* __restrict__ out, int n) {
    __shared__ float4 Ws[128 * 32];   // [k][granule]
    {
        const float4* W4 = (const float4*)W;
        for (int t = threadIdx.x; t < 4096; t += 256) Ws[t] = W4[t];
    }
    __syncthreads();

    int colg = threadIdx.x & 7;          // 0..7
    int rowg = threadIdx.x >> 3;         // 0..31
    int row0 = blockIdx.x * 128 + rowg * 4;

    const float4* Ap[4];
#pragma unroll
    for (int r = 0; r < 4; ++r) {
        int rr = min(row0 + r, n - 1);
        Ap[r] = (const float4*)(A + (size_t)rr * 128);
    }

    float acc[4][4][4];   // [row][granule m][elem j]
#pragma unroll
    for (int r = 0; r < 4; ++r)
#pragma unroll
        for (int m = 0; m < 4; ++m)
#pragma unroll
            for (int j = 0; j < 4; ++j) acc[r][m][j] = 0.0f;

    for (int k4 = 0; k4 < 32; ++k4) {
        float4 a[4];
#pragma unroll
        for (int r = 0; r < 4; ++r) a[r] = Ap[r][k4];
#pragma unroll
        for (int kk = 0; kk < 4; ++kk) {
            float4 w[4];
#pragma unroll
            for (int m = 0; m < 4; ++m) w[m] = Ws[(k4 * 4 + kk) * 32 + colg + 8 * m];
#pragma unroll
            for (int r = 0; r < 4; ++r) {
                float av = (&a[r].x)[kk];
#pragma unroll
                for (int m = 0; m < 4; ++m) {
#pragma unroll
                    for (int j = 0; j < 4; ++j) acc[r][m][j] += av * (&w[m].x)[j];
                }
            }
        }
    }

    float4 bz[4];
#pragma unroll
    for (int m = 0; m < 4; ++m) bz[m] = ((const float4*)bias)[colg + 8 * m];

#pragma unroll
    for (int r = 0; r < 4; ++r) {
        if (row0 + r < n) {
            float4* orow = (float4*)(out + (size_t)(row0 + r) * 128);
#pragma unroll
            for (int m = 0; m < 4; ++m) {
                float4 o;
                o.x = fmaxf(acc[r][m][0] + bz[m].x, 0.0f);
                o.y = fmaxf(acc[r][m][1] + bz[m].y, 0.0f);
                o.z = fmaxf(acc[r][m][2] + bz[m].z, 0.0f);
                o.w = fmaxf(acc[r][m][3] + bz[m].w, 0.0f);
                orow[colg + 8 * m] = o;
            }
        }
    }
}

// batch is sorted; block (g, s): binary-search graph bounds, reduce slice s.
__global__ void pool_partial(const float* __restrict__ h, const int* __restrict__ batch,
                             float* __restrict__ pooled, float* __restrict__ cntg,
                             int n, int splits) {
    int g = blockIdx.x / splits;
    int s = blockIdx.x % splits;
    __shared__ int sb[2];
    if (threadIdx.x == 0) {
        int lo = 0, hi = n;
        while (lo < hi) { int m = (lo + hi) >> 1; if (batch[m] < g) lo = m + 1; else hi = m; }
        sb[0] = lo;
        lo = 0; hi = n;
        while (lo < hi) { int m = (lo + hi) >> 1; if (batch[m] < g + 1) lo = m + 1; else hi = m; }
        sb[1] = lo;
    }
    __syncthreads();
    int start = sb[0], end = sb[1];
    int len = end - start;
    if (s == 0 && threadIdx.x == 0) cntg[g] = (float)len;
    int a = start + (int)((long long)len * s / splits);
    int b = start + (int)((long long)len * (s + 1) / splits);
    int col = threadIdx.x;
    float acc = 0.0f;
    for (int i = a; i < b; ++i) acc += h[(size_t)i * 128 + col];
    atomicAdd(&pooled[g * 128 + col], acc);
}

__global__ void fc_kernel(const float* __restrict__ pooled, const float* __restrict__ cntg,
                          const float* __restrict__ Wfc, const float* __restrict__ bfc,
                          float* __restrict__ out, int G, int O) {
    int gid = blockIdx.x * blockDim.x + threadIdx.x;
    if (gid >= G * O) return;
    int g = gid / O, o = gid % O;
    float inv = 1.0f / fmaxf(cntg[g], 1.0f);
    float acc = bfc[o];
    for (int k = 0; k < 128; ++k) acc += pooled[g * 128 + k] * inv * Wfc[k * O + o];
    out[gid] = acc;
}

extern "C" void kernel_launch(void* const* d_in, const int* in_sizes, int n_in,
                              void* d_out, int out_size, void* d_ws, size_t ws_size,
                              hipStream_t stream) {
    const float* x     = (const float*)d_in[0];
    const int*   ei    = (const int*)d_in[1];
    const float* ew    = (const float*)d_in[2];
    const int*   batch = (const int*)d_in[3];
    const float* W1    = (const float*)d_in[4];
    const float* b1    = (const float*)d_in[5];
    const float* W2    = (const float*)d_in[6];
    const float* b2    = (const float*)d_in[7];
    const float* Wfc   = (const float*)d_in[8];
    const float* bfc   = (const float*)d_in[9];
    float* out = (float*)d_out;

    const int n = in_sizes[0] / 128;   // 50000
    const int E = in_sizes[2];         // 640000
    const int O = in_sizes[9];         // 16
    const int G = out_size / O;        // 64
    const int* row = ei;
    const int* col = ei + E;
    const int NB = (n + 255) / 256;    // scan blocks (196)

    // Workspace carve (all 256B-aligned)
    char* p = (char*)d_ws;
    auto alloc = [&](size_t bytes) {
        char* r = p;
        p += (bytes + 255) & ~(size_t)255;
        return r;
    };
    float* dinv    = (float*)alloc((size_t)n * 4);
    int*   cnt     = (int*)alloc((size_t)n * 4);
    int*   rank    = (int*)alloc((size_t)E * 4);
    int*   rowptr  = (int*)alloc((size_t)(n + 1) * 4);
    int*   bsum    = (int*)alloc((size_t)NB * 4);
    int*   boff    = (int*)alloc((size_t)NB * 4);
    int2*  csr     = (int2*)alloc((size_t)E * 8);
    float* aggbuf  = (float*)alloc((size_t)n * 128 * 4);
    float* hbuf    = (float*)alloc((size_t)n * 128 * 4);
    float* pooled  = (float*)alloc((size_t)G * 128 * 4);
    float* cntg    = (float*)alloc((size_t)G * 4);

    // --- CSR build: one atomic pass + scan + atomic-free scatter ---
    init_kernel<<<(n + 255) / 256, 256, 0, stream>>>(cnt, pooled, cntg, n, G * 128, G);
    rank_kernel<<<(E + 255) / 256, 256, 0, stream>>>(col, cnt, rank, E);
    block_sum_kernel<<<NB, 256, 0, stream>>>(cnt, bsum, n);
    scan_bsum_kernel<<<1, 256, 0, stream>>>(bsum, boff, rowptr, n, NB);
    rowptr_kernel<<<NB, 256, 0, stream>>>(cnt, boff, rowptr, n);
    scatter_kernel<<<(E + 255) / 256, 256, 0, stream>>>(row, col, ew, rank, rowptr, csr, E);
    deginv_kernel<<<(n + 255) / 256, 256, 0, stream>>>(csr, rowptr, dinv, n);
    scale_kernel<<<(E + 255) / 256, 256, 0, stream>>>(csr, dinv, E);

    // --- layer 1: h1 = relu(agg(x) @ W1 + b1) ---
    agg_kernel<<<(n + 7) / 8, 256, 0, stream>>>(x, rowptr, csr, dinv, aggbuf, n);
    gemm_bias_relu<<<(n + 127) / 128, 256, 0, stream>>>(aggbuf, W1, b1, hbuf, n);

    // --- layer 2: h2 = relu(agg(h1) @ W2 + b2) ---
    agg_kernel<<<(n + 7) / 8, 256, 0, stream>>>(hbuf, rowptr, csr, dinv, aggbuf, n);
    gemm_bias_relu<<<(n + 127) / 128, 256, 0, stream>>>(aggbuf, W2, b2, hbuf, n);

    // --- pool + fc ---
    pool_partial<<<G * 8, 128, 0, stream>>>(hbuf, batch, pooled, cntg, n, 8);
    fc_kernel<<<(G * O + 255) / 256, 256, 0, stream>>>(pooled, cntg, Wfc, bfc, out, G, O);
}

// Round 6
// 300.887 us; speedup vs baseline: 1.7919x; 1.1695x over previous
//
#include <hip/hip_runtime.h>

// ---------------------------------------------------------------------------
// GraphNet: 2x GCNConv(128->128, relu) + global_mean_pool + Linear(128->16)
// N=50000 nodes, E=640000 edges, G=64 graphs. fp32 compute, indices int32.
// R6: gather payload in fp16 (halves gather bytes + footprint), dinv[src]
// folded into agg inner loop (scale pass removed), pool+fc fused, init+convert
// fused. CSR-by-dest: one atomic pass (rank), multiblock scan, atomic-free
// scatter. Agg: half-wave per node, fp16 h4 per lane, 4x unroll, fp32 acc.
// GEMM: W in LDS, strided-granule conflict-free tile, 4 rows x 16 cols.
// ---------------------------------------------------------------------------

typedef __attribute__((ext_vector_type(4))) float nfloat4;   // nt-store vec
typedef _Float16 h4 __attribute__((ext_vector_type(4)));     // 8B of fp16

// Fused: zero cnt histogram + convert x (fp32) -> x16 (fp16). nvec = n*32.
__global__ void init_convert_kernel(const float4* __restrict__ x4, h4* __restrict__ x16,
                                    int* __restrict__ cnt, int n, int nvec) {
    int i = blockIdx.x * blockDim.x + threadIdx.x;
    if (i < nvec) {
        float4 v = x4[i];
        h4 h;
        h.x = (_Float16)v.x; h.y = (_Float16)v.y;
        h.z = (_Float16)v.z; h.w = (_Float16)v.w;
        x16[i] = h;
    }
    if (i < n) cnt[i] = 0;
}

// ONE atomic per edge: rank within destination bucket + histogram.
__global__ void rank_kernel(const int* __restrict__ col, int* __restrict__ cnt,
                            int* __restrict__ rank, int E) {
    int e = blockIdx.x * blockDim.x + threadIdx.x;
    if (e >= E) return;
    rank[e] = atomicAdd(&cnt[col[e]], 1);
}

// --- 3-phase multiblock exclusive scan of cnt[0..n) -> rowptr[0..n] ---
__global__ void block_sum_kernel(const int* __restrict__ cnt, int* __restrict__ bsum, int n) {
    __shared__ int s[256];
    int i = blockIdx.x * 256 + threadIdx.x;
    s[threadIdx.x] = (i < n) ? cnt[i] : 0;
    __syncthreads();
    for (int off = 128; off > 0; off >>= 1) {
        if (threadIdx.x < off) s[threadIdx.x] += s[threadIdx.x + off];
        __syncthreads();
    }
    if (threadIdx.x == 0) bsum[blockIdx.x] = s[0];
}

__global__ void scan_bsum_kernel(const int* __restrict__ bsum, int* __restrict__ boff,
                                 int* __restrict__ rowptr, int n, int nb) {
    __shared__ int s[256];
    int t = threadIdx.x;
    int v = (t < nb) ? bsum[t] : 0;
    s[t] = v;
    __syncthreads();
    for (int off = 1; off < 256; off <<= 1) {
        int u = (t >= off) ? s[t - off] : 0;
        __syncthreads();
        s[t] += u;
        __syncthreads();
    }
    if (t < nb) boff[t] = s[t] - v;           // exclusive block offset
    if (t == nb - 1) rowptr[n] = s[t];        // grand total
}

__global__ void rowptr_kernel(const int* __restrict__ cnt, const int* __restrict__ boff,
                              int* __restrict__ rowptr, int n) {
    __shared__ int s[256];
    int i = blockIdx.x * 256 + threadIdx.x;
    int t = threadIdx.x;
    int v = (i < n) ? cnt[i] : 0;
    s[t] = v;
    __syncthreads();
    for (int off = 1; off < 256; off <<= 1) {
        int u = (t >= off) ? s[t - off] : 0;
        __syncthreads();
        s[t] += u;
        __syncthreads();
    }
    if (i < n) rowptr[i] = boff[blockIdx.x] + s[t] - v;
}

// Atomic-free scatter: pos = rowptr[col] + rank. Packed (src, raw ew bits).
__global__ void scatter_kernel(const int* __restrict__ row, const int* __restrict__ col,
                               const float* __restrict__ ew, const int* __restrict__ rank,
                               const int* __restrict__ rowptr, int2* __restrict__ csr, int E) {
    int e = blockIdx.x * blockDim.x + threadIdx.x;
    if (e >= E) return;
    int pos = rowptr[col[e]] + rank[e];
    int2 v;
    v.x = row[e];
    v.y = __float_as_int(ew[e]);
    csr[pos] = v;
}

// deg[i] = 1 + sum of incoming ew; dinv = rsqrt(deg). No atomics.
__global__ void deginv_kernel(const int2* __restrict__ csr, const int* __restrict__ rowptr,
                              float* __restrict__ dinv, int n) {
    int i = blockIdx.x * blockDim.x + threadIdx.x;
    if (i >= n) return;
    int beg = rowptr[i], end = rowptr[i + 1];
    float d = 1.0f;   // self-loop
    for (int k = beg; k < end; ++k) d += __int_as_float(csr[k].y);
    dinv[i] = rsqrtf(d);
}

// One half-wave (32 lanes) per node; lane owns 4 fp16 cols (8B). fp32 acc.
// w_e = dinv[src]*ew (dinv L2-resident, branches off csr load).
// out = dinv[dst] * ( sum_e w_e * x16[src_e]  +  dinv[dst] * x16[dst] )
__global__ __launch_bounds__(256) void agg_kernel(const h4* __restrict__ in16,
                                                  const int* __restrict__ rowptr,
                                                  const int2* __restrict__ csr,
                                                  const float* __restrict__ dinv,
                                                  float* __restrict__ out, int n) {
    int node = blockIdx.x * 8 + (threadIdx.x >> 5);
    if (node >= n) return;
    int lane = threadIdx.x & 31;
    float di = dinv[node];
    h4 v = in16[(size_t)node * 32 + lane];
    float ax = di * (float)v.x, ay = di * (float)v.y;
    float az = di * (float)v.z, aw = di * (float)v.w;
    int beg = rowptr[node], end = rowptr[node + 1];
    int idx = beg;
    for (; idx + 4 <= end; idx += 4) {
        int2 e0 = csr[idx + 0], e1 = csr[idx + 1], e2 = csr[idx + 2], e3 = csr[idx + 3];
        float w0 = dinv[e0.x] * __int_as_float(e0.y);
        float w1 = dinv[e1.x] * __int_as_float(e1.y);
        float w2 = dinv[e2.x] * __int_as_float(e2.y);
        float w3 = dinv[e3.x] * __int_as_float(e3.y);
        h4 u0 = in16[(size_t)e0.x * 32 + lane];
        h4 u1 = in16[(size_t)e1.x * 32 + lane];
        h4 u2 = in16[(size_t)e2.x * 32 + lane];
        h4 u3 = in16[(size_t)e3.x * 32 + lane];
        ax += w0 * (float)u0.x; ay += w0 * (float)u0.y; az += w0 * (float)u0.z; aw += w0 * (float)u0.w;
        ax += w1 * (float)u1.x; ay += w1 * (float)u1.y; az += w1 * (float)u1.z; aw += w1 * (float)u1.w;
        ax += w2 * (float)u2.x; ay += w2 * (float)u2.y; az += w2 * (float)u2.z; aw += w2 * (float)u2.w;
        ax += w3 * (float)u3.x; ay += w3 * (float)u3.y; az += w3 * (float)u3.z; aw += w3 * (float)u3.w;
    }
    for (; idx < end; ++idx) {
        int2 e0 = csr[idx];
        float ww = dinv[e0.x] * __int_as_float(e0.y);
        h4 u = in16[(size_t)e0.x * 32 + lane];
        ax += ww * (float)u.x; ay += ww * (float)u.y;
        az += ww * (float)u.z; aw += ww * (float)u.w;
    }
    nfloat4 r;
    r.x = ax * di; r.y = ay * di; r.z = az * di; r.w = aw * di;
    __builtin_nontemporal_store(r, &((nfloat4*)out)[(size_t)node * 32 + lane]);
}

// out[i][c] = relu(sum_k A[i][k]*W[k][c] + b[c]); A: n x 128 fp32, W: 128x128.
// Block 256 = 128 rows; thread: 4 rows x 16 cols as 4 strided float4 granules
// (conflict-free ds_read_b128, 8-lane broadcast). OUT16: write fp16 rows
// (consumed only by the next agg); else fp32.
template <int OUT16>
__global__ __launch_bounds__(256) void gemm_bias_relu(const float* __restrict__ A,
                                                      const float* __restrict__ W,
                                                      const float* __restrict__ bias,
                                                      float* __restrict__ out32,
                                                      h4* __restrict__ out16, int n) {
    __shared__ float4 Ws[128 * 32];   // [k][granule]
    {
        const float4* W4 = (const float4*)W;
        for (int t = threadIdx.x; t < 4096; t += 256) Ws[t] = W4[t];
    }
    __syncthreads();

    int colg = threadIdx.x & 7;          // 0..7
    int rowg = threadIdx.x >> 3;         // 0..31
    int row0 = blockIdx.x * 128 + rowg * 4;

    const float4* Ap[4];
#pragma unroll
    for (int r = 0; r < 4; ++r) {
        int rr = min(row0 + r, n - 1);
        Ap[r] = (const float4*)(A + (size_t)rr * 128);
    }

    float acc[4][4][4];   // [row][granule m][elem j]
#pragma unroll
    for (int r = 0; r < 4; ++r)
#pragma unroll
        for (int m = 0; m < 4; ++m)
#pragma unroll
            for (int j = 0; j < 4; ++j) acc[r][m][j] = 0.0f;

    for (int k4 = 0; k4 < 32; ++k4) {
        float4 a[4];
#pragma unroll
        for (int r = 0; r < 4; ++r) a[r] = Ap[r][k4];
#pragma unroll
        for (int kk = 0; kk < 4; ++kk) {
            float4 w[4];
#pragma unroll
            for (int m = 0; m < 4; ++m) w[m] = Ws[(k4 * 4 + kk) * 32 + colg + 8 * m];
#pragma unroll
            for (int r = 0; r < 4; ++r) {
                float av = (&a[r].x)[kk];
#pragma unroll
                for (int m = 0; m < 4; ++m) {
#pragma unroll
                    for (int j = 0; j < 4; ++j) acc[r][m][j] += av * (&w[m].x)[j];
                }
            }
        }
    }

    float4 bz[4];
#pragma unroll
    for (int m = 0; m < 4; ++m) bz[m] = ((const float4*)bias)[colg + 8 * m];

#pragma unroll
    for (int r = 0; r < 4; ++r) {
        if (row0 + r < n) {
#pragma unroll
            for (int m = 0; m < 4; ++m) {
                float o0 = fmaxf(acc[r][m][0] + bz[m].x, 0.0f);
                float o1 = fmaxf(acc[r][m][1] + bz[m].y, 0.0f);
                float o2 = fmaxf(acc[r][m][2] + bz[m].z, 0.0f);
                float o3 = fmaxf(acc[r][m][3] + bz[m].w, 0.0f);
                if (OUT16) {
                    h4 hv;
                    hv.x = (_Float16)o0; hv.y = (_Float16)o1;
                    hv.z = (_Float16)o2; hv.w = (_Float16)o3;
                    out16[(size_t)(row0 + r) * 32 + colg + 8 * m] = hv;
                } else {
                    float4 o; o.x = o0; o.y = o1; o.z = o2; o.w = o3;
                    ((float4*)(out32 + (size_t)(row0 + r) * 128))[colg + 8 * m] = o;
                }
            }
        }
    }
}

// Fused mean-pool + FC. One block per graph (batch sorted): binary-search
// bounds, 8-way row-split float4 column reduce, LDS tree, then 16-wide FC.
__global__ __launch_bounds__(256) void poolfc_kernel(const float* __restrict__ h,
                                                     const int* __restrict__ batch,
                                                     const float* __restrict__ Wfc,
                                                     const float* __restrict__ bfc,
                                                     float* __restrict__ out, int n, int O) {
    int g = blockIdx.x;
    __shared__ int sb[2];
    __shared__ float4 red[256];
    __shared__ float pooled[128];
    int t = threadIdx.x;
    if (t < 2) {
        int target = g + t;
        int lo = 0, hi = n;
        while (lo < hi) { int m = (lo + hi) >> 1; if (batch[m] < target) lo = m + 1; else hi = m; }
        sb[t] = lo;
    }
    __syncthreads();
    int start = sb[0], end = sb[1], len = end - start;
    int gq = t & 31;     // column granule
    int seg = t >> 5;    // 0..7 row split
    const float4* h4p = (const float4*)h;
    float4 acc; acc.x = acc.y = acc.z = acc.w = 0.0f;
    for (int i = start + seg; i < end; i += 8) {
        float4 v = h4p[(size_t)i * 32 + gq];
        acc.x += v.x; acc.y += v.y; acc.z += v.z; acc.w += v.w;
    }
    red[seg * 32 + gq] = acc;
    __syncthreads();
    if (t < 128) {   // seg 0..3 += seg 4..7
        float4 a = red[t], b = red[t + 128];
        a.x += b.x; a.y += b.y; a.z += b.z; a.w += b.w;
        red[t] = a;
    }
    __syncthreads();
    if (t < 64) {
        float4 a = red[t], b = red[t + 64];
        a.x += b.x; a.y += b.y; a.z += b.z; a.w += b.w;
        red[t] = a;
    }
    __syncthreads();
    if (t < 32) {
        float4 a = red[t], b = red[t + 32];
        float inv = (len > 0) ? 1.0f / (float)len : 0.0f;
        pooled[t * 4 + 0] = (a.x + b.x) * inv;
        pooled[t * 4 + 1] = (a.y + b.y) * inv;
        pooled[t * 4 + 2] = (a.z + b.z) * inv;
        pooled[t * 4 + 3] = (a.w + b.w) * inv;
    }
    __syncthreads();
    if (t < O) {
        float a = bfc[t];
        for (int k = 0; k < 128; ++k) a += pooled[k] * Wfc[k * O + t];
        out[g * O + t] = a;
    }
}

extern "C" void kernel_launch(void* const* d_in, const int* in_sizes, int n_in,
                              void* d_out, int out_size, void* d_ws, size_t ws_size,
                              hipStream_t stream) {
    const float* x     = (const float*)d_in[0];
    const int*   ei    = (const int*)d_in[1];
    const float* ew    = (const float*)d_in[2];
    const int*   batch = (const int*)d_in[3];
    const float* W1    = (const float*)d_in[4];
    const float* b1    = (const float*)d_in[5];
    const float* W2    = (const float*)d_in[6];
    const float* b2    = (const float*)d_in[7];
    const float* Wfc   = (const float*)d_in[8];
    const float* bfc   = (const float*)d_in[9];
    float* out = (float*)d_out;

    const int n = in_sizes[0] / 128;   // 50000
    const int E = in_sizes[2];         // 640000
    const int O = in_sizes[9];         // 16
    const int G = out_size / O;        // 64
    const int* row = ei;
    const int* col = ei + E;
    const int NB = (n + 255) / 256;    // scan blocks (196)
    const int nvec = n * 32;           // h4 granules in x16

    // Workspace carve (all 256B-aligned)
    char* p = (char*)d_ws;
    auto alloc = [&](size_t bytes) {
        char* r = p;
        p += (bytes + 255) & ~(size_t)255;
        return r;
    };
    float* dinv    = (float*)alloc((size_t)n * 4);
    int*   cnt     = (int*)alloc((size_t)n * 4);
    int*   rank    = (int*)alloc((size_t)E * 4);
    int*   rowptr  = (int*)alloc((size_t)(n + 1) * 4);
    int*   bsum    = (int*)alloc((size_t)NB * 4);
    int*   boff    = (int*)alloc((size_t)NB * 4);
    int2*  csr     = (int2*)alloc((size_t)E * 8);
    h4*    x16     = (h4*)alloc((size_t)n * 128 * 2);    // fp16 gather payload
    h4*    h16     = (h4*)alloc((size_t)n * 128 * 2);    // fp16 layer-1 output
    float* aggbuf  = (float*)alloc((size_t)n * 128 * 4);
    float* hbuf    = (float*)alloc((size_t)n * 128 * 4);

    // --- preprocessing: convert + CSR build (one atomic pass) ---
    init_convert_kernel<<<(nvec + 255) / 256, 256, 0, stream>>>((const float4*)x, x16, cnt, n, nvec);
    rank_kernel<<<(E + 255) / 256, 256, 0, stream>>>(col, cnt, rank, E);
    block_sum_kernel<<<NB, 256, 0, stream>>>(cnt, bsum, n);
    scan_bsum_kernel<<<1, 256, 0, stream>>>(bsum, boff, rowptr, n, NB);
    rowptr_kernel<<<NB, 256, 0, stream>>>(cnt, boff, rowptr, n);
    scatter_kernel<<<(E + 255) / 256, 256, 0, stream>>>(row, col, ew, rank, rowptr, csr, E);
    deginv_kernel<<<(n + 255) / 256, 256, 0, stream>>>(csr, rowptr, dinv, n);

    // --- layer 1: h16 = fp16(relu(agg(x16) @ W1 + b1)) ---
    agg_kernel<<<(n + 7) / 8, 256, 0, stream>>>(x16, rowptr, csr, dinv, aggbuf, n);
    gemm_bias_relu<1><<<(n + 127) / 128, 256, 0, stream>>>(aggbuf, W1, b1, nullptr, h16, n);

    // --- layer 2: hbuf = relu(agg(h16) @ W2 + b2) ---
    agg_kernel<<<(n + 7) / 8, 256, 0, stream>>>(h16, rowptr, csr, dinv, aggbuf, n);
    gemm_bias_relu<0><<<(n + 127) / 128, 256, 0, stream>>>(aggbuf, W2, b2, hbuf, nullptr, n);

    // --- fused mean-pool + fc ---
    poolfc_kernel<<<G, 256, 0, stream>>>(hbuf, batch, Wfc, bfc, out, n, O);
}